// Round 5
// baseline (446.133 us; speedup 1.0000x reference)
//
#include <hip/hip_runtime.h>

#define NQ    4
#define DIM   16
#define NL    3
#define HD    128
#define KROWS 4
#define NTHR  256
#define NBLK  1024
#define PIF   3.14159265358979323846f

__global__ __launch_bounds__(NTHR, 4) void rqa_kernel(
    const float* __restrict__ edge,   // (N,128)
    const float* __restrict__ W,      // (4,128)
    const float* __restrict__ b,      // (4,)
    const float* __restrict__ qw,     // (3,4,3)
    float* __restrict__ out, int N)
{
    __shared__ float4 rotm4[NL * NQ];   // (a_re, a_im, b_re, b_im) per Rot gate

    const int tid = threadIdx.x;
    if (tid < NL * NQ) {
        float phi = qw[tid * 3 + 0];
        float th  = qw[tid * 3 + 1];
        float om  = qw[tid * 3 + 2];
        float ct, st, ca, sa, cb, sb;
        sincosf(0.5f * th, &st, &ct);
        sincosf(0.5f * (phi + om), &sa, &ca);
        sincosf(0.5f * (phi - om), &sb, &cb);
        rotm4[tid] = make_float4(ca * ct, -sa * ct, -cb * st, -sb * st);
    }
    __syncthreads();

    const unsigned G  = NBLK * NTHR;      // 262144
    const unsigned Nu = (unsigned)N;
    unsigned r = blockIdx.x * NTHR + tid;

    float4 x[8];            // staging block, reused per quarter
    float acc[NQ], nacc[NQ];

    // -------- prologue: full dot for first row --------
    {
        const unsigned rc = r < Nu ? r : Nu - 1;
        const float4* __restrict__ rowp = (const float4*)(edge + (size_t)rc * HD);
        #pragma unroll
        for (int o = 0; o < NQ; ++o) nacc[o] = 0.f;
        #pragma unroll
        for (int q = 0; q < 4; ++q) {
            #pragma unroll
            for (int j = 0; j < 8; ++j) x[j] = rowp[q * 8 + j];
            #pragma unroll
            for (int j = 0; j < 8; ++j) {
                const int c0 = q * 32 + j * 4;
                #pragma unroll
                for (int o = 0; o < NQ; ++o)
                    nacc[o] += x[j].x * W[o*HD + c0 + 0] + x[j].y * W[o*HD + c0 + 1]
                             + x[j].z * W[o*HD + c0 + 2] + x[j].w * W[o*HD + c0 + 3];
            }
        }
        #pragma unroll
        for (int o = 0; o < NQ; ++o) acc[o] = nacc[o];
    }

    // -------- pipelined main loop: circuit of row k-1 overlaps loads of row k --------
    #pragma unroll 1
    for (int k = 1; k < KROWS; ++k) {
        const unsigned rn  = r + G;
        const unsigned rnc = rn < Nu ? rn : Nu - 1;
        const float4* __restrict__ rowp = (const float4*)(edge + (size_t)rnc * HD);

        // issue quarter-0 loads for next row
        #pragma unroll
        for (int j = 0; j < 8; ++j) x[j] = rowp[j];

        // angles for current row
        float cy[NQ], sy[NQ];
        #pragma unroll
        for (int w = 0; w < NQ; ++w) {
            float a = PIF * tanhf(acc[w] + b[w]);
            sincosf(0.5f * a, &sy[w], &cy[w]);
        }
        float sr[DIM], si[DIM];
        #pragma unroll
        for (int n = 0; n < DIM; ++n) { sr[n] = 0.f; si[n] = 0.f; }
        sr[0] = 1.f;
        #pragma unroll
        for (int o = 0; o < NQ; ++o) nacc[o] = 0.f;

        #pragma unroll
        for (int l = 0; l < NL; ++l) {
            // fused gates U = Rot * RY on wires 0..3  (wire w <-> bit 3-w)
            #pragma unroll
            for (int w = 0; w < NQ; ++w) {
                const float4 g = rotm4[l * 4 + w];
                const float c = cy[w], s = sy[w];
                const float m0r = g.x * c + g.z * s;
                const float m0i = g.y * c + g.w * s;
                const float m1r = g.z * c - g.x * s;
                const float m1i = g.w * c - g.y * s;
                const int str = 1 << (3 - w);
                #pragma unroll
                for (int i0 = 0; i0 < DIM; ++i0) {
                    if (i0 & str) continue;
                    const int i1 = i0 | str;
                    const float s0r = sr[i0], s0i = si[i0], s1r = sr[i1], s1i = si[i1];
                    sr[i0] =  m0r*s0r - m0i*s0i + m1r*s1r - m1i*s1i;
                    si[i0] =  m0r*s0i + m0i*s0r + m1r*s1i + m1i*s1r;
                    sr[i1] = -m1r*s0r - m1i*s0i + m0r*s1r + m0i*s1i;
                    si[i1] = -m1r*s0i + m1i*s0r + m0r*s1i - m0i*s1r;
                }
            }
            // CNOT ring
            #pragma unroll
            for (int w = 0; w < NQ; ++w) {
                const int cb_ = 1 << (3 - w);
                const int tb_ = 1 << (3 - ((w + 1) & 3));
                #pragma unroll
                for (int n = 0; n < DIM; ++n) {
                    if ((n & cb_) && !(n & tb_)) {
                        const int m = n | tb_;
                        float t0 = sr[n]; sr[n] = sr[m]; sr[m] = t0;
                        float t1 = si[n]; si[n] = si[m]; si[m] = t1;
                    }
                }
            }
            // consume staged quarter l; then issue quarter l+1
            #pragma unroll
            for (int j = 0; j < 8; ++j) {
                const int c0 = l * 32 + j * 4;
                #pragma unroll
                for (int o = 0; o < NQ; ++o)
                    nacc[o] += x[j].x * W[o*HD + c0 + 0] + x[j].y * W[o*HD + c0 + 1]
                             + x[j].z * W[o*HD + c0 + 2] + x[j].w * W[o*HD + c0 + 3];
            }
            #pragma unroll
            for (int j = 0; j < 8; ++j) x[j] = rowp[(l + 1) * 8 + j];
        }

        // readout for current row
        float z = 0.f;
        #pragma unroll
        for (int n = 0; n < DIM; ++n) {
            const float p = sr[n]*sr[n] + si[n]*si[n];
            z = (n < 8) ? (z + p) : (z - p);
        }
        if (r < Nu) out[r] = 1.f / (1.f + expf(-z));

        // final quarter FMA (q = 3)
        #pragma unroll
        for (int j = 0; j < 8; ++j) {
            const int c0 = 96 + j * 4;
            #pragma unroll
            for (int o = 0; o < NQ; ++o)
                nacc[o] += x[j].x * W[o*HD + c0 + 0] + x[j].y * W[o*HD + c0 + 1]
                         + x[j].z * W[o*HD + c0 + 2] + x[j].w * W[o*HD + c0 + 3];
        }
        #pragma unroll
        for (int o = 0; o < NQ; ++o) acc[o] = nacc[o];
        r = rn;
    }

    // -------- epilogue: circuit for last row --------
    {
        float cy[NQ], sy[NQ];
        #pragma unroll
        for (int w = 0; w < NQ; ++w) {
            float a = PIF * tanhf(acc[w] + b[w]);
            sincosf(0.5f * a, &sy[w], &cy[w]);
        }
        float sr[DIM], si[DIM];
        #pragma unroll
        for (int n = 0; n < DIM; ++n) { sr[n] = 0.f; si[n] = 0.f; }
        sr[0] = 1.f;
        #pragma unroll
        for (int l = 0; l < NL; ++l) {
            #pragma unroll
            for (int w = 0; w < NQ; ++w) {
                const float4 g = rotm4[l * 4 + w];
                const float c = cy[w], s = sy[w];
                const float m0r = g.x * c + g.z * s;
                const float m0i = g.y * c + g.w * s;
                const float m1r = g.z * c - g.x * s;
                const float m1i = g.w * c - g.y * s;
                const int str = 1 << (3 - w);
                #pragma unroll
                for (int i0 = 0; i0 < DIM; ++i0) {
                    if (i0 & str) continue;
                    const int i1 = i0 | str;
                    const float s0r = sr[i0], s0i = si[i0], s1r = sr[i1], s1i = si[i1];
                    sr[i0] =  m0r*s0r - m0i*s0i + m1r*s1r - m1i*s1i;
                    si[i0] =  m0r*s0i + m0i*s0r + m1r*s1i + m1i*s1r;
                    sr[i1] = -m1r*s0r - m1i*s0i + m0r*s1r + m0i*s1i;
                    si[i1] = -m1r*s0i + m1i*s0r + m0r*s1i - m0i*s1r;
                }
            }
            #pragma unroll
            for (int w = 0; w < NQ; ++w) {
                const int cb_ = 1 << (3 - w);
                const int tb_ = 1 << (3 - ((w + 1) & 3));
                #pragma unroll
                for (int n = 0; n < DIM; ++n) {
                    if ((n & cb_) && !(n & tb_)) {
                        const int m = n | tb_;
                        float t0 = sr[n]; sr[n] = sr[m]; sr[m] = t0;
                        float t1 = si[n]; si[n] = si[m]; si[m] = t1;
                    }
                }
            }
        }
        float z = 0.f;
        #pragma unroll
        for (int n = 0; n < DIM; ++n) {
            const float p = sr[n]*sr[n] + si[n]*si[n];
            z = (n < 8) ? (z + p) : (z - p);
        }
        if (r < Nu) out[r] = 1.f / (1.f + expf(-z));
    }
}

extern "C" void kernel_launch(void* const* d_in, const int* in_sizes, int n_in,
                              void* d_out, int out_size, void* d_ws, size_t ws_size,
                              hipStream_t stream) {
    const float* edge = (const float*)d_in[0];
    const float* W    = (const float*)d_in[1];
    const float* b    = (const float*)d_in[2];
    const float* qw   = (const float*)d_in[3];
    float* out = (float*)d_out;

    const int N = in_sizes[0] / HD;   // 800000; NBLK*NTHR*KROWS = 1048576 covers it
    rqa_kernel<<<dim3(NBLK), dim3(NTHR), 0, stream>>>(edge, W, b, qw, out, N);
}

// Round 7
// 131.557 us; speedup vs baseline: 3.3912x; 3.3912x over previous
//
#include <hip/hip_runtime.h>

#define NQ    4
#define DIM   16
#define NL    3
#define HD    128
#define NTHR  256
#define PIF   3.14159265358979323846f

// ================= kernel 1: streaming projection =================
// ws[r] = edge[r,:] . W^T + b   (one float4 per row)
// R3-validated geometry: 16 lanes per row; per iteration a wave covers
// 4 rows (grp = lane>>4) with two 256B-contiguous segments per row
// (cols sub and sub+16). Exact HBM fetch: every float4 read exactly once.
__global__ __launch_bounds__(NTHR) void proj_kernel(
    const float* __restrict__ edge,   // (N,128)
    const float* __restrict__ W,      // (4,128)
    const float* __restrict__ b,      // (4,)
    float4* __restrict__ ws,          // (N) angle accumulators
    int N)
{
    __shared__ float4 part[NTHR][5];   // [row][quad-slot 0..3], [4] pad

    const int tid  = threadIdx.x;
    const int lane = tid & 63;
    const int wid  = tid >> 6;
    const int sub  = lane & 15;
    const int grp  = lane >> 4;

    const float4* __restrict__ Wv = (const float4*)W;
    const float4 w00 = Wv[0*32 + sub], w01 = Wv[0*32 + sub + 16];
    const float4 w10 = Wv[1*32 + sub], w11 = Wv[1*32 + sub + 16];
    const float4 w20 = Wv[2*32 + sub], w21 = Wv[2*32 + sub + 16];
    const float4 w30 = Wv[3*32 + sub], w31 = Wv[3*32 + sub + 16];

    const unsigned Nu = (unsigned)N;
    const unsigned blockRow0 = blockIdx.x * NTHR;
    const float4* __restrict__ ep = (const float4*)edge;

    // depth-2 software pipeline over the 16 row-groups
    unsigned r0 = blockRow0 + wid * 64 + grp;
    if (r0 >= Nu) r0 = Nu - 1;
    float4 xa0 = ep[(size_t)r0 * 32 + sub];
    float4 xa1 = ep[(size_t)r0 * 32 + sub + 16];

    #pragma unroll
    for (int p = 0; p < 16; ++p) {
        float4 xb0, xb1;
        if (p < 15) {
            unsigned rn = blockRow0 + wid * 64 + (p + 1) * 4 + grp;
            if (rn >= Nu) rn = Nu - 1;
            xb0 = ep[(size_t)rn * 32 + sub];
            xb1 = ep[(size_t)rn * 32 + sub + 16];
        }
        float a0 = xa0.x*w00.x + xa0.y*w00.y + xa0.z*w00.z + xa0.w*w00.w
                 + xa1.x*w01.x + xa1.y*w01.y + xa1.z*w01.z + xa1.w*w01.w;
        float a1 = xa0.x*w10.x + xa0.y*w10.y + xa0.z*w10.z + xa0.w*w10.w
                 + xa1.x*w11.x + xa1.y*w11.y + xa1.z*w11.z + xa1.w*w11.w;
        float a2 = xa0.x*w20.x + xa0.y*w20.y + xa0.z*w20.z + xa0.w*w20.w
                 + xa1.x*w21.x + xa1.y*w21.y + xa1.z*w21.z + xa1.w*w21.w;
        float a3 = xa0.x*w30.x + xa0.y*w30.y + xa0.z*w30.z + xa0.w*w30.w
                 + xa1.x*w31.x + xa1.y*w31.y + xa1.z*w31.z + xa1.w*w31.w;
        // quad reduction (lanes sub, sub^1, sub^2, sub^3 share a row-quarter)
        a0 += __shfl_xor(a0, 1); a0 += __shfl_xor(a0, 2);
        a1 += __shfl_xor(a1, 1); a1 += __shfl_xor(a1, 2);
        a2 += __shfl_xor(a2, 1); a2 += __shfl_xor(a2, 2);
        a3 += __shfl_xor(a3, 1); a3 += __shfl_xor(a3, 2);
        if ((sub & 3) == 0)
            part[wid * 64 + p * 4 + grp][sub >> 2] = make_float4(a0, a1, a2, a3);
        xa0 = xb0; xa1 = xb1;
    }
    __syncthreads();

    const unsigned gid = blockRow0 + tid;
    if (gid < Nu) {
        const float4 p0 = part[tid][0];
        const float4 p1 = part[tid][1];
        const float4 p2 = part[tid][2];
        const float4 p3 = part[tid][3];
        ws[gid] = make_float4(p0.x + p1.x + p2.x + p3.x + b[0],
                              p0.y + p1.y + p2.y + p3.y + b[1],
                              p0.z + p1.z + p2.z + p3.z + b[2],
                              p0.w + p1.w + p2.w + p3.w + b[3]);
    }
}

// ================= kernel 2: register-resident circuit =================
__global__ __launch_bounds__(NTHR) void circ_kernel(
    const float4* __restrict__ ws,    // (N) projection results
    const float* __restrict__ qw,     // (3,4,3)
    float* __restrict__ out, int N)
{
    __shared__ float4 rotm4[NL * NQ];

    const int tid = threadIdx.x;
    if (tid < NL * NQ) {
        float phi = qw[tid * 3 + 0];
        float th  = qw[tid * 3 + 1];
        float om  = qw[tid * 3 + 2];
        float ct, st, ca, sa, cb, sb;
        sincosf(0.5f * th, &st, &ct);
        sincosf(0.5f * (phi + om), &sa, &ca);
        sincosf(0.5f * (phi - om), &sb, &cb);
        rotm4[tid] = make_float4(ca * ct, -sa * ct, -cb * st, -sb * st);
    }
    __syncthreads();

    const unsigned gid = blockIdx.x * NTHR + tid;
    if (gid >= (unsigned)N) return;

    const float4 accv = ws[gid];
    const float accf[NQ] = {accv.x, accv.y, accv.z, accv.w};

    float cy[NQ], sy[NQ];
    #pragma unroll
    for (int w = 0; w < NQ; ++w) {
        float a = PIF * tanhf(accf[w]);
        sincosf(0.5f * a, &sy[w], &cy[w]);
    }

    float sr[DIM], si[DIM];
    #pragma unroll
    for (int n = 0; n < DIM; ++n) { sr[n] = 0.f; si[n] = 0.f; }
    sr[0] = 1.f;

    #pragma unroll
    for (int l = 0; l < NL; ++l) {
        // fused gate U = Rot * RY  (wire w <-> bit 3-w; wire 0 = MSB)
        #pragma unroll
        for (int w = 0; w < NQ; ++w) {
            const float4 g = rotm4[l * 4 + w];
            const float c = cy[w], s = sy[w];
            const float m0r = g.x * c + g.z * s;
            const float m0i = g.y * c + g.w * s;
            const float m1r = g.z * c - g.x * s;
            const float m1i = g.w * c - g.y * s;
            const int str = 1 << (3 - w);
            #pragma unroll
            for (int i0 = 0; i0 < DIM; ++i0) {
                if (i0 & str) continue;
                const int i1 = i0 | str;
                const float s0r = sr[i0], s0i = si[i0], s1r = sr[i1], s1i = si[i1];
                sr[i0] =  m0r*s0r - m0i*s0i + m1r*s1r - m1i*s1i;
                si[i0] =  m0r*s0i + m0i*s0r + m1r*s1i + m1i*s1r;
                sr[i1] = -m1r*s0r - m1i*s0i + m0r*s1r + m0i*s1i;
                si[i1] = -m1r*s0i + m1i*s0r + m0r*s1i - m0i*s1r;
            }
        }
        // CNOT ring (0,1),(1,2),(2,3),(3,0)
        #pragma unroll
        for (int w = 0; w < NQ; ++w) {
            const int cb_ = 1 << (3 - w);
            const int tb_ = 1 << (3 - ((w + 1) & 3));
            #pragma unroll
            for (int n = 0; n < DIM; ++n) {
                if ((n & cb_) && !(n & tb_)) {
                    const int m = n | tb_;
                    float t0 = sr[n]; sr[n] = sr[m]; sr[m] = t0;
                    float t1 = si[n]; si[n] = si[m]; si[m] = t1;
                }
            }
        }
    }

    float z = 0.f;
    #pragma unroll
    for (int n = 0; n < DIM; ++n) {
        const float p = sr[n] * sr[n] + si[n] * si[n];
        z = (n < 8) ? (z + p) : (z - p);
    }
    out[gid] = 1.f / (1.f + expf(-z));
}

extern "C" void kernel_launch(void* const* d_in, const int* in_sizes, int n_in,
                              void* d_out, int out_size, void* d_ws, size_t ws_size,
                              hipStream_t stream) {
    const float* edge = (const float*)d_in[0];
    const float* W    = (const float*)d_in[1];
    const float* b    = (const float*)d_in[2];
    const float* qw   = (const float*)d_in[3];
    float* out  = (float*)d_out;
    float4* ws  = (float4*)d_ws;

    const int N = in_sizes[0] / HD;          // 800000
    const int blocks = (N + NTHR - 1) / NTHR; // 3125 (exact: N % 256 == 0)
    proj_kernel<<<dim3(blocks), dim3(NTHR), 0, stream>>>(edge, W, b, ws, N);
    circ_kernel<<<dim3(blocks), dim3(NTHR), 0, stream>>>(ws, qw, out, N);
}

// Round 8
// 129.736 us; speedup vs baseline: 3.4388x; 1.0140x over previous
//
#include <hip/hip_runtime.h>

#define NQ    4
#define DIM   16
#define NL    3
#define HD    128
#define NTHR  256
#define PIF   3.14159265358979323846f

// ================= kernel 1: streaming projection =================
// ws[r] = edge[r,:] . W^T + b   (one float4 per row)
// 16 lanes per row; per iteration a wave covers 4 rows (grp = lane>>4)
// with two 256B-contiguous segments per row (cols sub, sub+16).
// Exact HBM fetch; 4-deep prefetch ring -> 8KB in flight per wave.
__global__ __launch_bounds__(NTHR) void proj_kernel(
    const float* __restrict__ edge,   // (N,128)
    const float* __restrict__ W,      // (4,128)
    const float* __restrict__ b,      // (4,)
    float4* __restrict__ ws,          // (N) angle accumulators
    int N)
{
    __shared__ float4 part[NTHR][5];   // [row][quad-slot 0..3], [4] pad

    const int tid  = threadIdx.x;
    const int lane = tid & 63;
    const int wid  = tid >> 6;
    const int sub  = lane & 15;
    const int grp  = lane >> 4;

    const float4* __restrict__ Wv = (const float4*)W;
    const float4 w00 = Wv[0*32 + sub], w01 = Wv[0*32 + sub + 16];
    const float4 w10 = Wv[1*32 + sub], w11 = Wv[1*32 + sub + 16];
    const float4 w20 = Wv[2*32 + sub], w21 = Wv[2*32 + sub + 16];
    const float4 w30 = Wv[3*32 + sub], w31 = Wv[3*32 + sub + 16];

    const unsigned Nu = (unsigned)N;
    const unsigned waveRow0 = blockIdx.x * NTHR + wid * 64;
    const float4* __restrict__ ep = (const float4*)edge;

    // 4-deep prefetch ring (static indices after full unroll)
    float4 xs0[4], xs1[4];
    #pragma unroll
    for (int d = 0; d < 4; ++d) {
        unsigned r = waveRow0 + d * 4 + grp;
        if (r >= Nu) r = Nu - 1;
        xs0[d] = ep[(size_t)r * 32 + sub];
        xs1[d] = ep[(size_t)r * 32 + sub + 16];
    }

    #pragma unroll
    for (int p = 0; p < 16; ++p) {
        const float4 xa0 = xs0[p & 3];
        const float4 xa1 = xs1[p & 3];
        if (p + 4 < 16) {
            unsigned rn = waveRow0 + (p + 4) * 4 + grp;
            if (rn >= Nu) rn = Nu - 1;
            xs0[p & 3] = ep[(size_t)rn * 32 + sub];
            xs1[p & 3] = ep[(size_t)rn * 32 + sub + 16];
        }
        float a0 = xa0.x*w00.x + xa0.y*w00.y + xa0.z*w00.z + xa0.w*w00.w
                 + xa1.x*w01.x + xa1.y*w01.y + xa1.z*w01.z + xa1.w*w01.w;
        float a1 = xa0.x*w10.x + xa0.y*w10.y + xa0.z*w10.z + xa0.w*w10.w
                 + xa1.x*w11.x + xa1.y*w11.y + xa1.z*w11.z + xa1.w*w11.w;
        float a2 = xa0.x*w20.x + xa0.y*w20.y + xa0.z*w20.z + xa0.w*w20.w
                 + xa1.x*w21.x + xa1.y*w21.y + xa1.z*w21.z + xa1.w*w21.w;
        float a3 = xa0.x*w30.x + xa0.y*w30.y + xa0.z*w30.z + xa0.w*w30.w
                 + xa1.x*w31.x + xa1.y*w31.y + xa1.z*w31.z + xa1.w*w31.w;
        // quad reduction (lanes sub, sub^1, sub^2, sub^3 share a row-quarter)
        a0 += __shfl_xor(a0, 1); a0 += __shfl_xor(a0, 2);
        a1 += __shfl_xor(a1, 1); a1 += __shfl_xor(a1, 2);
        a2 += __shfl_xor(a2, 1); a2 += __shfl_xor(a2, 2);
        a3 += __shfl_xor(a3, 1); a3 += __shfl_xor(a3, 2);
        if ((sub & 3) == 0)
            part[wid * 64 + p * 4 + grp][sub >> 2] = make_float4(a0, a1, a2, a3);
    }
    __syncthreads();

    const unsigned gid = blockIdx.x * NTHR + tid;
    if (gid < Nu) {
        const float4 p0 = part[tid][0];
        const float4 p1 = part[tid][1];
        const float4 p2 = part[tid][2];
        const float4 p3 = part[tid][3];
        ws[gid] = make_float4(p0.x + p1.x + p2.x + p3.x + b[0],
                              p0.y + p1.y + p2.y + p3.y + b[1],
                              p0.z + p1.z + p2.z + p3.z + b[2],
                              p0.w + p1.w + p2.w + p3.w + b[3]);
    }
}

// ================= kernel 2: register-resident circuit =================
__global__ __launch_bounds__(NTHR) void circ_kernel(
    const float4* __restrict__ ws,    // (N) projection results
    const float* __restrict__ qw,     // (3,4,3)
    float* __restrict__ out, int N)
{
    __shared__ float4 rotm4[NL * NQ];

    const int tid = threadIdx.x;
    if (tid < NL * NQ) {
        float phi = qw[tid * 3 + 0];
        float th  = qw[tid * 3 + 1];
        float om  = qw[tid * 3 + 2];
        float ct, st, ca, sa, cb, sb;
        sincosf(0.5f * th, &st, &ct);
        sincosf(0.5f * (phi + om), &sa, &ca);
        sincosf(0.5f * (phi - om), &sb, &cb);
        rotm4[tid] = make_float4(ca * ct, -sa * ct, -cb * st, -sb * st);
    }
    __syncthreads();

    const unsigned gid = blockIdx.x * NTHR + tid;
    if (gid >= (unsigned)N) return;

    const float4 accv = ws[gid];
    const float accf[NQ] = {accv.x, accv.y, accv.z, accv.w};

    float cy[NQ], sy[NQ];
    #pragma unroll
    for (int w = 0; w < NQ; ++w) {
        float a = PIF * tanhf(accf[w]);
        sincosf(0.5f * a, &sy[w], &cy[w]);
    }

    float sr[DIM], si[DIM];
    #pragma unroll
    for (int n = 0; n < DIM; ++n) { sr[n] = 0.f; si[n] = 0.f; }
    sr[0] = 1.f;

    #pragma unroll
    for (int l = 0; l < NL; ++l) {
        // fused gate U = Rot * RY  (wire w <-> bit 3-w; wire 0 = MSB)
        #pragma unroll
        for (int w = 0; w < NQ; ++w) {
            const float4 g = rotm4[l * 4 + w];
            const float c = cy[w], s = sy[w];
            const float m0r = g.x * c + g.z * s;
            const float m0i = g.y * c + g.w * s;
            const float m1r = g.z * c - g.x * s;
            const float m1i = g.w * c - g.y * s;
            const int str = 1 << (3 - w);
            #pragma unroll
            for (int i0 = 0; i0 < DIM; ++i0) {
                if (i0 & str) continue;
                const int i1 = i0 | str;
                const float s0r = sr[i0], s0i = si[i0], s1r = sr[i1], s1i = si[i1];
                sr[i0] =  m0r*s0r - m0i*s0i + m1r*s1r - m1i*s1i;
                si[i0] =  m0r*s0i + m0i*s0r + m1r*s1i + m1i*s1r;
                sr[i1] = -m1r*s0r - m1i*s0i + m0r*s1r + m0i*s1i;
                si[i1] = -m1r*s0i + m1i*s0r + m0r*s1i - m0i*s1r;
            }
        }
        // CNOT ring (0,1),(1,2),(2,3),(3,0)
        #pragma unroll
        for (int w = 0; w < NQ; ++w) {
            const int cb_ = 1 << (3 - w);
            const int tb_ = 1 << (3 - ((w + 1) & 3));
            #pragma unroll
            for (int n = 0; n < DIM; ++n) {
                if ((n & cb_) && !(n & tb_)) {
                    const int m = n | tb_;
                    float t0 = sr[n]; sr[n] = sr[m]; sr[m] = t0;
                    float t1 = si[n]; si[n] = si[m]; si[m] = t1;
                }
            }
        }
    }

    float z = 0.f;
    #pragma unroll
    for (int n = 0; n < DIM; ++n) {
        const float p = sr[n] * sr[n] + si[n] * si[n];
        z = (n < 8) ? (z + p) : (z - p);
    }
    out[gid] = 1.f / (1.f + expf(-z));
}

extern "C" void kernel_launch(void* const* d_in, const int* in_sizes, int n_in,
                              void* d_out, int out_size, void* d_ws, size_t ws_size,
                              hipStream_t stream) {
    const float* edge = (const float*)d_in[0];
    const float* W    = (const float*)d_in[1];
    const float* b    = (const float*)d_in[2];
    const float* qw   = (const float*)d_in[3];
    float* out  = (float*)d_out;
    float4* ws  = (float4*)d_ws;

    const int N = in_sizes[0] / HD;           // 800000
    const int blocks = (N + NTHR - 1) / NTHR; // 3125
    proj_kernel<<<dim3(blocks), dim3(NTHR), 0, stream>>>(edge, W, b, ws, N);
    circ_kernel<<<dim3(blocks), dim3(NTHR), 0, stream>>>(ws, qw, out, N);
}

// Round 9
// 127.500 us; speedup vs baseline: 3.4991x; 1.0175x over previous
//
#include <hip/hip_runtime.h>

#define NQ    4
#define DIM   16
#define NL    3
#define HD    128
#define NTHR  256
#define PIF   3.14159265358979323846f

// ---- native transcendental wrappers (single VOP1 each, ISA §3) ----
__device__ __forceinline__ float fast_exp2(float y) { float r; asm("v_exp_f32 %0, %1" : "=v"(r) : "v"(y)); return r; }
__device__ __forceinline__ float fast_rcp (float y) { float r; asm("v_rcp_f32 %0, %1" : "=v"(r) : "v"(y)); return r; }
__device__ __forceinline__ float sin2pi  (float u) { float r; asm("v_sin_f32 %0, %1" : "=v"(r) : "v"(u)); return r; }
__device__ __forceinline__ float cos2pi  (float u) { float r; asm("v_cos_f32 %0, %1" : "=v"(r) : "v"(u)); return r; }

// ================= kernel 1: streaming projection (UNCHANGED from R8) =================
__global__ __launch_bounds__(NTHR) void proj_kernel(
    const float* __restrict__ edge,   // (N,128)
    const float* __restrict__ W,      // (4,128)
    const float* __restrict__ b,      // (4,)
    float4* __restrict__ ws,          // (N) angle accumulators
    int N)
{
    __shared__ float4 part[NTHR][5];   // [row][quad-slot 0..3], [4] pad

    const int tid  = threadIdx.x;
    const int lane = tid & 63;
    const int wid  = tid >> 6;
    const int sub  = lane & 15;
    const int grp  = lane >> 4;

    const float4* __restrict__ Wv = (const float4*)W;
    const float4 w00 = Wv[0*32 + sub], w01 = Wv[0*32 + sub + 16];
    const float4 w10 = Wv[1*32 + sub], w11 = Wv[1*32 + sub + 16];
    const float4 w20 = Wv[2*32 + sub], w21 = Wv[2*32 + sub + 16];
    const float4 w30 = Wv[3*32 + sub], w31 = Wv[3*32 + sub + 16];

    const unsigned Nu = (unsigned)N;
    const unsigned waveRow0 = blockIdx.x * NTHR + wid * 64;
    const float4* __restrict__ ep = (const float4*)edge;

    float4 xs0[4], xs1[4];
    #pragma unroll
    for (int d = 0; d < 4; ++d) {
        unsigned r = waveRow0 + d * 4 + grp;
        if (r >= Nu) r = Nu - 1;
        xs0[d] = ep[(size_t)r * 32 + sub];
        xs1[d] = ep[(size_t)r * 32 + sub + 16];
    }

    #pragma unroll
    for (int p = 0; p < 16; ++p) {
        const float4 xa0 = xs0[p & 3];
        const float4 xa1 = xs1[p & 3];
        if (p + 4 < 16) {
            unsigned rn = waveRow0 + (p + 4) * 4 + grp;
            if (rn >= Nu) rn = Nu - 1;
            xs0[p & 3] = ep[(size_t)rn * 32 + sub];
            xs1[p & 3] = ep[(size_t)rn * 32 + sub + 16];
        }
        float a0 = xa0.x*w00.x + xa0.y*w00.y + xa0.z*w00.z + xa0.w*w00.w
                 + xa1.x*w01.x + xa1.y*w01.y + xa1.z*w01.z + xa1.w*w01.w;
        float a1 = xa0.x*w10.x + xa0.y*w10.y + xa0.z*w10.z + xa0.w*w10.w
                 + xa1.x*w11.x + xa1.y*w11.y + xa1.z*w11.z + xa1.w*w11.w;
        float a2 = xa0.x*w20.x + xa0.y*w20.y + xa0.z*w20.z + xa0.w*w20.w
                 + xa1.x*w21.x + xa1.y*w21.y + xa1.z*w21.z + xa1.w*w21.w;
        float a3 = xa0.x*w30.x + xa0.y*w30.y + xa0.z*w30.z + xa0.w*w30.w
                 + xa1.x*w31.x + xa1.y*w31.y + xa1.z*w31.z + xa1.w*w31.w;
        a0 += __shfl_xor(a0, 1); a0 += __shfl_xor(a0, 2);
        a1 += __shfl_xor(a1, 1); a1 += __shfl_xor(a1, 2);
        a2 += __shfl_xor(a2, 1); a2 += __shfl_xor(a2, 2);
        a3 += __shfl_xor(a3, 1); a3 += __shfl_xor(a3, 2);
        if ((sub & 3) == 0)
            part[wid * 64 + p * 4 + grp][sub >> 2] = make_float4(a0, a1, a2, a3);
    }
    __syncthreads();

    const unsigned gid = blockIdx.x * NTHR + tid;
    if (gid < Nu) {
        const float4 p0 = part[tid][0];
        const float4 p1 = part[tid][1];
        const float4 p2 = part[tid][2];
        const float4 p3 = part[tid][3];
        ws[gid] = make_float4(p0.x + p1.x + p2.x + p3.x + b[0],
                              p0.y + p1.y + p2.y + p3.y + b[1],
                              p0.z + p1.z + p2.z + p3.z + b[2],
                              p0.w + p1.w + p2.w + p3.w + b[3]);
    }
}

// ================= kernel 2: circuit with native transcendentals =================
__global__ __launch_bounds__(NTHR) void circ_kernel(
    const float4* __restrict__ ws,    // (N) projection results
    const float* __restrict__ qw,     // (3,4,3)
    float* __restrict__ out, int N)
{
    __shared__ float4 rotm4[NL * NQ];

    const int tid = threadIdx.x;
    if (tid < NL * NQ) {
        float phi = qw[tid * 3 + 0];
        float th  = qw[tid * 3 + 1];
        float om  = qw[tid * 3 + 2];
        float ct, st, ca, sa, cb, sb;
        sincosf(0.5f * th, &st, &ct);
        sincosf(0.5f * (phi + om), &sa, &ca);
        sincosf(0.5f * (phi - om), &sb, &cb);
        rotm4[tid] = make_float4(ca * ct, -sa * ct, -cb * st, -sb * st);
    }
    __syncthreads();

    const unsigned gid = blockIdx.x * NTHR + tid;
    if (gid >= (unsigned)N) return;

    const float4 accv = ws[gid];
    const float accf[NQ] = {accv.x, accv.y, accv.z, accv.w};

    // t = tanh(acc) = 1 - 2/(e^{2acc}+1)  (v_exp + v_rcp)
    // angle theta = pi*t; sin/cos(theta/2) = sin/cos(2*pi*(t/4))  (v_sin/v_cos, revolutions)
    float cy[NQ], sy[NQ];
    #pragma unroll
    for (int w = 0; w < NQ; ++w) {
        const float e = fast_exp2(accf[w] * 2.8853900817779268f);  // e^{2x} = 2^{2x*log2(e)}
        const float t = fmaf(-2.f, fast_rcp(e + 1.f), 1.f);
        const float u = t * 0.25f;                                  // |u| <= 0.25 rev
        sy[w] = sin2pi(u);
        cy[w] = cos2pi(u);
    }

    float sr[DIM], si[DIM];
    #pragma unroll
    for (int n = 0; n < DIM; ++n) { sr[n] = 0.f; si[n] = 0.f; }
    sr[0] = 1.f;

    #pragma unroll
    for (int l = 0; l < NL; ++l) {
        // fused gate U = Rot * RY  (wire w <-> bit 3-w; wire 0 = MSB)
        #pragma unroll
        for (int w = 0; w < NQ; ++w) {
            const float4 g = rotm4[l * 4 + w];
            const float c = cy[w], s = sy[w];
            const float m0r = g.x * c + g.z * s;
            const float m0i = g.y * c + g.w * s;
            const float m1r = g.z * c - g.x * s;
            const float m1i = g.w * c - g.y * s;
            const int str = 1 << (3 - w);
            #pragma unroll
            for (int i0 = 0; i0 < DIM; ++i0) {
                if (i0 & str) continue;
                const int i1 = i0 | str;
                const float s0r = sr[i0], s0i = si[i0], s1r = sr[i1], s1i = si[i1];
                sr[i0] =  m0r*s0r - m0i*s0i + m1r*s1r - m1i*s1i;
                si[i0] =  m0r*s0i + m0i*s0r + m1r*s1i + m1i*s1r;
                sr[i1] = -m1r*s0r - m1i*s0i + m0r*s1r + m0i*s1i;
                si[i1] = -m1r*s0i + m1i*s0r + m0r*s1i - m0i*s1r;
            }
        }
        // CNOT ring (0,1),(1,2),(2,3),(3,0)
        #pragma unroll
        for (int w = 0; w < NQ; ++w) {
            const int cb_ = 1 << (3 - w);
            const int tb_ = 1 << (3 - ((w + 1) & 3));
            #pragma unroll
            for (int n = 0; n < DIM; ++n) {
                if ((n & cb_) && !(n & tb_)) {
                    const int m = n | tb_;
                    float t0 = sr[n]; sr[n] = sr[m]; sr[m] = t0;
                    float t1 = si[n]; si[n] = si[m]; si[m] = t1;
                }
            }
        }
    }

    float z = 0.f;
    #pragma unroll
    for (int n = 0; n < DIM; ++n) {
        const float p = sr[n] * sr[n] + si[n] * si[n];
        z = (n < 8) ? (z + p) : (z - p);
    }
    // sigmoid(z) = 1/(1 + 2^{-z*log2(e)})
    out[gid] = fast_rcp(1.f + fast_exp2(z * -1.4426950408889634f));
}

extern "C" void kernel_launch(void* const* d_in, const int* in_sizes, int n_in,
                              void* d_out, int out_size, void* d_ws, size_t ws_size,
                              hipStream_t stream) {
    const float* edge = (const float*)d_in[0];
    const float* W    = (const float*)d_in[1];
    const float* b    = (const float*)d_in[2];
    const float* qw   = (const float*)d_in[3];
    float* out  = (float*)d_out;
    float4* ws  = (float4*)d_ws;

    const int N = in_sizes[0] / HD;           // 800000
    const int blocks = (N + NTHR - 1) / NTHR; // 3125
    proj_kernel<<<dim3(blocks), dim3(NTHR), 0, stream>>>(edge, W, b, ws, N);
    circ_kernel<<<dim3(blocks), dim3(NTHR), 0, stream>>>(ws, qw, out, N);
}